// Round 2
// baseline (666.646 us; speedup 1.0000x reference)
//
#include <hip/hip_runtime.h>
#include <hip/hip_bf16.h>

typedef unsigned short u16;
typedef unsigned int   u32;

#define DI __device__ __forceinline__

constexpr int TBL  = 2535;     // (2*8-1)*(2*7-1)*(2*7-1)
constexpr int NTOK = 50176;    // 128 windows * 392 tokens

DI float b2f(u16 u){ return __uint_as_float(((u32)u)<<16); }
DI u16 f2b(float f){
  u32 u = __float_as_uint(f);
  return (u16)((u + 0x7fffu + ((u>>16)&1u)) >> 16);
}
DI float ldf(const void* p, int i, int isf32){
  return isf32 ? ((const float*)p)[i] : b2f(((const u16*)p)[i]);
}

// ---------------- 0) dtype detector: low u16 of each u32 word viewed as bf16.
// f32 data -> random mantissa bits -> ~88% wild exponents. bf16 data -> ~0%.
__global__ void k_detect(const u32* __restrict__ xw, int* __restrict__ flag){
  __shared__ int cnt;
  if (threadIdx.x == 0) cnt = 0;
  __syncthreads();
  int local = 0;
  for (int k = threadIdx.x; k < 4096; k += 256){
    u32 w = xw[k];
    u16 lo = (u16)w;
    u32 e = (lo >> 7) & 0xFF;
    if (lo != 0 && (e >= 143 || e <= 111)) local++;
  }
  atomicAdd(&cnt, local);
  __syncthreads();
  if (threadIdx.x == 0) *flag = (cnt > 1000) ? 1 : 0;
}

// ---------------- 1) CPB MLP table: table16[h][t] = 16*sigmoid(mlp(coords[t]))[h]
__global__ void k_cpb(const void* __restrict__ w1, const void* __restrict__ b1,
                      const void* __restrict__ w2, const int* __restrict__ flag,
                      float* __restrict__ table16){
  const int isf32 = *flag;
  int t = blockIdx.x, lane = threadIdx.x;
  int i = t/169; int r = t - i*169; int j = r/13; int k = r - j*13;
  float v0 = 8.f*(float)(i-7)/7.f, v1 = 8.f*(float)(j-6)/6.f, v2 = 8.f*(float)(k-6)/6.f;
  float c0 = copysignf(log2f(fabsf(v0)+1.f)*(1.f/3.f), v0);
  float c1 = copysignf(log2f(fabsf(v1)+1.f)*(1.f/3.f), v1);
  float c2 = copysignf(log2f(fabsf(v2)+1.f)*(1.f/3.f), v2);
  float a0=0.f,a1=0.f,a2=0.f,a3=0.f;
  for (int hh = lane; hh < 512; hh += 64){
    float a = c0*ldf(w1,hh*3,isf32) + c1*ldf(w1,hh*3+1,isf32)
            + c2*ldf(w1,hh*3+2,isf32) + ldf(b1,hh,isf32);
    a = fmaxf(a, 0.f);
    a0 += a*ldf(w2,hh,isf32);       a1 += a*ldf(w2,512+hh,isf32);
    a2 += a*ldf(w2,1024+hh,isf32);  a3 += a*ldf(w2,1536+hh,isf32);
  }
  #pragma unroll
  for (int off=32; off; off>>=1){
    a0 += __shfl_xor(a0, off); a1 += __shfl_xor(a1, off);
    a2 += __shfl_xor(a2, off); a3 += __shfl_xor(a3, off);
  }
  if (lane==0){
    table16[t]       = 16.f/(1.f+__expf(-a0));
    table16[TBL+t]   = 16.f/(1.f+__expf(-a1));
    table16[2*TBL+t] = 16.f/(1.f+__expf(-a2));
    table16[3*TBL+t] = 16.f/(1.f+__expf(-a3));
  }
}

// ---------------- 2) expand to bias16[h][n][m]
__global__ void k_bias(const float* __restrict__ table16, float* __restrict__ bias16){
  int n = blockIdx.x, h = blockIdx.y;
  int td = n/49; int r2 = n - td*49; int th = r2/7; int tw = r2 - th*7;
  const float* tb = table16 + h*TBL;
  float* o = bias16 + ((size_t)h*392 + n)*392;
  for (int m = threadIdx.x; m < 392; m += 128){
    int sd = m/49; int q2 = m - sd*49; int sh = q2/7; int sw = q2 - sh*7;
    int idx = (td - sd + 7)*169 + (th - sh + 6)*13 + (tw - sw + 6);
    o[m] = tb[idx];
  }
}

// ---------------- 3) QKV GEMM (roll + window partition fused in the gather)
__global__ __launch_bounds__(256,3) void k_qkv(const void* __restrict__ x,
    const void* __restrict__ qw, const void* __restrict__ qb,
    const int* __restrict__ flag, u16* __restrict__ qkvbuf){
  __shared__ __align__(16) u16 xT[128*72];    // [k][tok], pad 72
  __shared__ __align__(16) u16 wT[128*136];   // [k][oc],  pad 136
  const int isf32 = *flag;
  const int tid = threadIdx.x;
  const int g0 = blockIdx.x*64;
  const int which = blockIdx.y;
  { // stage x (transposed), gather through roll+window mapping
    int trow = tid>>2, c = (tid&3)*32;
    int g = g0 + trow;
    int win = g/392, tt = g - win*392;
    int dwi = win>>6, hwi = (win>>3)&7, wwi = win&7;
    int td = tt/49; int r2 = tt - td*49; int th = r2/7; int tw = r2 - th*7;
    int pd = dwi*8 + td + 4; if (pd >= 16) pd -= 16;
    int ph = hwi*7 + th + 3; if (ph >= 56) ph -= 56;
    int pw = wwi*7 + tw + 3; if (pw >= 56) pw -= 56;
    size_t pos = (size_t)((pd*56 + ph)*56 + pw)*128 + c;
    if (isf32){
      const float4* src = (const float4*)((const float*)x + pos);
      #pragma unroll
      for (int u=0; u<8; ++u){
        float4 a = src[u];
        int kb = c + u*4;
        xT[(kb+0)*72+trow] = f2b(a.x);  xT[(kb+1)*72+trow] = f2b(a.y);
        xT[(kb+2)*72+trow] = f2b(a.z);  xT[(kb+3)*72+trow] = f2b(a.w);
      }
    } else {
      const uint4* src = (const uint4*)((const u16*)x + pos);
      #pragma unroll
      for (int u=0; u<4; ++u){
        uint4 a = src[u];
        int kb = c + u*8;
        xT[(kb+0)*72+trow] = (u16)a.x;  xT[(kb+1)*72+trow] = (u16)(a.x>>16);
        xT[(kb+2)*72+trow] = (u16)a.y;  xT[(kb+3)*72+trow] = (u16)(a.y>>16);
        xT[(kb+4)*72+trow] = (u16)a.z;  xT[(kb+5)*72+trow] = (u16)(a.z>>16);
        xT[(kb+6)*72+trow] = (u16)a.w;  xT[(kb+7)*72+trow] = (u16)(a.w>>16);
      }
    }
  }
  { // stage weight rows [which*128 .. +127]
    int orow = tid>>1, c2 = (tid&1)*64;
    size_t pos = (size_t)(which*128 + orow)*128 + c2;
    if (isf32){
      const float4* src = (const float4*)((const float*)qw + pos);
      #pragma unroll
      for (int u=0; u<16; ++u){
        float4 a = src[u];
        int kb = c2 + u*4;
        wT[(kb+0)*136+orow] = f2b(a.x);  wT[(kb+1)*136+orow] = f2b(a.y);
        wT[(kb+2)*136+orow] = f2b(a.z);  wT[(kb+3)*136+orow] = f2b(a.w);
      }
    } else {
      const uint4* src = (const uint4*)((const u16*)qw + pos);
      #pragma unroll
      for (int u=0; u<8; ++u){
        uint4 a = src[u];
        int kb = c2 + u*8;
        wT[(kb+0)*136+orow] = (u16)a.x;  wT[(kb+1)*136+orow] = (u16)(a.x>>16);
        wT[(kb+2)*136+orow] = (u16)a.y;  wT[(kb+3)*136+orow] = (u16)(a.y>>16);
        wT[(kb+4)*136+orow] = (u16)a.z;  wT[(kb+5)*136+orow] = (u16)(a.z>>16);
        wT[(kb+6)*136+orow] = (u16)a.w;  wT[(kb+7)*136+orow] = (u16)(a.w>>16);
      }
    }
  }
  __syncthreads();
  const int tg = tid & 15, og = tid >> 4;
  const int t0 = tg*4, o0 = og*8;
  float acc[4][8];
  #pragma unroll
  for (int j2=0;j2<4;++j2)
    #pragma unroll
    for (int i2=0;i2<8;++i2) acc[j2][i2] = 0.f;
  for (int k=0;k<128;++k){
    ushort4 xa = *(const ushort4*)&xT[k*72 + t0];
    uint4   wb = *(const uint4*)  &wT[k*136 + o0];
    float xv[4] = { b2f(xa.x), b2f(xa.y), b2f(xa.z), b2f(xa.w) };
    float wv[8];
    wv[0]=__uint_as_float(wb.x<<16); wv[1]=__uint_as_float(wb.x&0xffff0000u);
    wv[2]=__uint_as_float(wb.y<<16); wv[3]=__uint_as_float(wb.y&0xffff0000u);
    wv[4]=__uint_as_float(wb.z<<16); wv[5]=__uint_as_float(wb.z&0xffff0000u);
    wv[6]=__uint_as_float(wb.w<<16); wv[7]=__uint_as_float(wb.w&0xffff0000u);
    #pragma unroll
    for (int j2=0;j2<4;++j2)
      #pragma unroll
      for (int i2=0;i2<8;++i2) acc[j2][i2] = fmaf(xv[j2], wv[i2], acc[j2][i2]);
  }
  const int head = o0 >> 5;
  const int chb  = o0 & 31;
  float bv[8];
  #pragma unroll
  for (int i2=0;i2<8;++i2)
    bv[i2] = (which==1) ? 0.f : ldf(qb, which*128 + o0 + i2, isf32);  // k-bias zeroed
  #pragma unroll
  for (int j2=0;j2<4;++j2){
    int g = g0 + t0 + j2;
    u16* dst = qkvbuf + ((size_t)(which*4+head)*NTOK + g)*32 + chb;
    uint4 val;
    val.x = (u32)f2b(acc[j2][0]+bv[0]) | ((u32)f2b(acc[j2][1]+bv[1])<<16);
    val.y = (u32)f2b(acc[j2][2]+bv[2]) | ((u32)f2b(acc[j2][3]+bv[3])<<16);
    val.z = (u32)f2b(acc[j2][4]+bv[4]) | ((u32)f2b(acc[j2][5]+bv[5])<<16);
    val.w = (u32)f2b(acc[j2][6]+bv[6]) | ((u32)f2b(acc[j2][7]+bv[7])<<16);
    *(uint4*)dst = val;
  }
}

// ---------------- 4) attention: one block per (window, head)
__global__ __launch_bounds__(256,2) void k_attn(const u16* __restrict__ qkv,
    const float* __restrict__ bias16, const void* __restrict__ lsc,
    const int* __restrict__ flag, u16* __restrict__ aout){
  __shared__ __align__(16) u16 klds[392*36];     // K rows, stride 36 (28224 B)
  __shared__ __align__(16) u16 vT[32*396];       // V transposed [ch][m] (25344 B)
  __shared__ __align__(16) float Pbuf[4][1568];  // per-wave P, 4 rows (25088 B)
  __shared__ float kinv[392];
  __shared__ int   cntk[392];
  const int isf32 = *flag;
  const int tid = threadIdx.x;
  const int win = blockIdx.x, h = blockIdx.y;
  const int dwi = win>>6, hwi = (win>>3)&7, wwi = win&7;
  const u16* qg = qkv + ((size_t)(0*4 + h)*NTOK + (size_t)win*392)*32;
  const u16* kg = qkv + ((size_t)(1*4 + h)*NTOK + (size_t)win*392)*32;
  const u16* vg = qkv + ((size_t)(2*4 + h)*NTOK + (size_t)win*392)*32;
  for (int idx = tid; idx < 1568; idx += 256){
    int m = idx>>2, c = idx&3;
    uint4 a = ((const uint4*)kg)[idx];
    ushort4 lo = make_ushort4((u16)a.x,(u16)(a.x>>16),(u16)a.y,(u16)(a.y>>16));
    ushort4 hi = make_ushort4((u16)a.z,(u16)(a.z>>16),(u16)a.w,(u16)(a.w>>16));
    *(ushort4*)&klds[m*36 + c*8]     = lo;
    *(ushort4*)&klds[m*36 + c*8 + 4] = hi;
    uint4 b = ((const uint4*)vg)[idx];
    int ch = c*8;
    vT[(ch+0)*396 + m] = (u16)b.x;  vT[(ch+1)*396 + m] = (u16)(b.x>>16);
    vT[(ch+2)*396 + m] = (u16)b.y;  vT[(ch+3)*396 + m] = (u16)(b.y>>16);
    vT[(ch+4)*396 + m] = (u16)b.z;  vT[(ch+5)*396 + m] = (u16)(b.z>>16);
    vT[(ch+6)*396 + m] = (u16)b.w;  vT[(ch+7)*396 + m] = (u16)(b.w>>16);
  }
  for (int t = tid; t < 392; t += 256){  // shift-mask region id per token
    int td = t/49; int r2 = t - td*49; int th = r2/7; int tw = r2 - th*7;
    int gd = dwi*8 + td, gh = hwi*7 + th, gw = wwi*7 + tw;
    int rd = (gd < 8) ? 0 : ((gd < 12) ? 1 : 2);
    int rh = (gh < 49) ? 0 : ((gh < 53) ? 1 : 2);
    int rw = (gw < 49) ? 0 : ((gw < 53) ? 1 : 2);
    cntk[t] = rd*9 + rh*3 + rw;
  }
  __syncthreads();
  for (int m = tid; m < 392; m += 256){
    float ss = 0.f;
    #pragma unroll
    for (int e=0;e<8;++e){
      ushort4 kv = *(const ushort4*)&klds[m*36 + e*4];
      float f0=b2f(kv.x),f1=b2f(kv.y),f2=b2f(kv.z),f3=b2f(kv.w);
      ss += f0*f0+f1*f1+f2*f2+f3*f3;
    }
    kinv[m] = 1.f/fmaxf(sqrtf(ss), 1e-12f);
  }
  __syncthreads();
  const float ls = isf32 ? ((const float*)lsc)[h] : b2f(((const u16*)lsc)[h]);
  const float scale = __expf(fminf(ls, 4.60517019f));
  const int wave = tid>>6, lane = tid&63;
  const float* bias_h = bias16 + (size_t)h*392*392;
  float* Pw = Pbuf[wave];
  for (int g4 = wave; g4 < 98; g4 += 4){
    const int n0 = g4*4;
    for (int r=0;r<4;++r){
      const int n = n0 + r;
      const uint4* qp = (const uint4*)(qg + (size_t)n*32);
      uint4 q0=qp[0], q1=qp[1], q2=qp[2], q3=qp[3];
      float qf[32];
      qf[0] =__uint_as_float(q0.x<<16); qf[1] =__uint_as_float(q0.x&0xffff0000u);
      qf[2] =__uint_as_float(q0.y<<16); qf[3] =__uint_as_float(q0.y&0xffff0000u);
      qf[4] =__uint_as_float(q0.z<<16); qf[5] =__uint_as_float(q0.z&0xffff0000u);
      qf[6] =__uint_as_float(q0.w<<16); qf[7] =__uint_as_float(q0.w&0xffff0000u);
      qf[8] =__uint_as_float(q1.x<<16); qf[9] =__uint_as_float(q1.x&0xffff0000u);
      qf[10]=__uint_as_float(q1.y<<16); qf[11]=__uint_as_float(q1.y&0xffff0000u);
      qf[12]=__uint_as_float(q1.z<<16); qf[13]=__uint_as_float(q1.z&0xffff0000u);
      qf[14]=__uint_as_float(q1.w<<16); qf[15]=__uint_as_float(q1.w&0xffff0000u);
      qf[16]=__uint_as_float(q2.x<<16); qf[17]=__uint_as_float(q2.x&0xffff0000u);
      qf[18]=__uint_as_float(q2.y<<16); qf[19]=__uint_as_float(q2.y&0xffff0000u);
      qf[20]=__uint_as_float(q2.z<<16); qf[21]=__uint_as_float(q2.z&0xffff0000u);
      qf[22]=__uint_as_float(q2.w<<16); qf[23]=__uint_as_float(q2.w&0xffff0000u);
      qf[24]=__uint_as_float(q3.x<<16); qf[25]=__uint_as_float(q3.x&0xffff0000u);
      qf[26]=__uint_as_float(q3.y<<16); qf[27]=__uint_as_float(q3.y&0xffff0000u);
      qf[28]=__uint_as_float(q3.z<<16); qf[29]=__uint_as_float(q3.z&0xffff0000u);
      qf[30]=__uint_as_float(q3.w<<16); qf[31]=__uint_as_float(q3.w&0xffff0000u);
      float ss = 0.f;
      #pragma unroll
      for (int e=0;e<32;++e) ss = fmaf(qf[e], qf[e], ss);
      const float qs = scale / fmaxf(sqrtf(ss), 1e-12f);
      const int cn = cntk[n];
      const float* brow = bias_h + (size_t)n*392;
      float s[7];
      #pragma unroll
      for (int i=0;i<7;++i){
        int m = lane + (i<<6);
        if (m < 392){
          const u16* kr = &klds[m*36];
          float d = 0.f;
          #pragma unroll
          for (int e=0;e<8;++e){
            ushort4 kv = *(const ushort4*)&kr[e*4];
            d = fmaf(qf[4*e+0], b2f(kv.x), d);
            d = fmaf(qf[4*e+1], b2f(kv.y), d);
            d = fmaf(qf[4*e+2], b2f(kv.z), d);
            d = fmaf(qf[4*e+3], b2f(kv.w), d);
          }
          float sv = d * kinv[m] * qs + brow[m];
          sv += (cntk[m]==cn) ? 0.f : -100.f;
          s[i] = sv;
        } else {
          s[i] = -1e30f;
        }
      }
      float mx = s[0];
      #pragma unroll
      for (int i=1;i<7;++i) mx = fmaxf(mx, s[i]);
      #pragma unroll
      for (int off=32; off; off>>=1) mx = fmaxf(mx, __shfl_xor(mx, off));
      float ps = 0.f; float p[7];
      #pragma unroll
      for (int i=0;i<7;++i){ p[i] = __expf(s[i]-mx); ps += p[i]; }
      #pragma unroll
      for (int off=32; off; off>>=1) ps += __shfl_xor(ps, off);
      const float rinv = 1.f/ps;
      #pragma unroll
      for (int i=0;i<7;++i){
        int m = lane + (i<<6);
        if (m < 392) Pw[r*392 + m] = p[i]*rinv;
      }
    }
    { // pass B: PV, lane = (ch, m-half)
      const int ch = lane & 31, mh = lane >> 5;
      const u16* vr = &vT[ch*396 + mh*196];
      const float* p0 = &Pw[0*392 + mh*196];
      const float* p1 = &Pw[1*392 + mh*196];
      const float* p2 = &Pw[2*392 + mh*196];
      const float* p3 = &Pw[3*392 + mh*196];
      float o0=0.f,o1=0.f,o2=0.f,o3=0.f;
      for (int t2=0;t2<49;++t2){
        ushort4 vv = *(const ushort4*)&vr[t2*4];
        float v0=b2f(vv.x),v1=b2f(vv.y),v2=b2f(vv.z),v3=b2f(vv.w);
        float4 a0 = *(const float4*)&p0[t2*4];
        float4 a1 = *(const float4*)&p1[t2*4];
        float4 a2 = *(const float4*)&p2[t2*4];
        float4 a3 = *(const float4*)&p3[t2*4];
        o0 += a0.x*v0 + a0.y*v1 + a0.z*v2 + a0.w*v3;
        o1 += a1.x*v0 + a1.y*v1 + a1.z*v2 + a1.w*v3;
        o2 += a2.x*v0 + a2.y*v1 + a2.z*v2 + a2.w*v3;
        o3 += a3.x*v0 + a3.y*v1 + a3.z*v2 + a3.w*v3;
      }
      o0 += __shfl_down(o0, 32);
      o1 += __shfl_down(o1, 32);
      o2 += __shfl_down(o2, 32);
      o3 += __shfl_down(o3, 32);
      if (lane < 32){
        size_t base = ((size_t)(win*392 + n0))*128 + h*32 + ch;
        aout[base      ] = f2b(o0);
        aout[base + 128] = f2b(o1);
        aout[base + 256] = f2b(o2);
        aout[base + 384] = f2b(o3);
      }
    }
  }
}

// ---------------- 5) projection GEMM + window reverse + roll-back
__global__ __launch_bounds__(256,3) void k_proj(const u16* __restrict__ ain,
    const void* __restrict__ pwt, const void* __restrict__ pb,
    const int* __restrict__ flag, void* __restrict__ out){
  __shared__ __align__(16) u16 xT[128*72];
  __shared__ __align__(16) u16 wT[128*136];
  const int isf32 = *flag;
  const int tid = threadIdx.x;
  const int g0 = blockIdx.x*64;
  {
    int trow = tid>>2, c = (tid&3)*32;
    const uint4* src = (const uint4*)(ain + (size_t)(g0+trow)*128 + c);
    #pragma unroll
    for (int u=0; u<4; ++u){
      uint4 a = src[u];
      int kb = c + u*8;
      xT[(kb+0)*72+trow] = (u16)a.x;  xT[(kb+1)*72+trow] = (u16)(a.x>>16);
      xT[(kb+2)*72+trow] = (u16)a.y;  xT[(kb+3)*72+trow] = (u16)(a.y>>16);
      xT[(kb+4)*72+trow] = (u16)a.z;  xT[(kb+5)*72+trow] = (u16)(a.z>>16);
      xT[(kb+6)*72+trow] = (u16)a.w;  xT[(kb+7)*72+trow] = (u16)(a.w>>16);
    }
  }
  {
    int orow = tid>>1, c2 = (tid&1)*64;
    size_t pos = (size_t)orow*128 + c2;
    if (isf32){
      const float4* src = (const float4*)((const float*)pwt + pos);
      #pragma unroll
      for (int u=0; u<16; ++u){
        float4 a = src[u];
        int kb = c2 + u*4;
        wT[(kb+0)*136+orow] = f2b(a.x);  wT[(kb+1)*136+orow] = f2b(a.y);
        wT[(kb+2)*136+orow] = f2b(a.z);  wT[(kb+3)*136+orow] = f2b(a.w);
      }
    } else {
      const uint4* src = (const uint4*)((const u16*)pwt + pos);
      #pragma unroll
      for (int u=0; u<8; ++u){
        uint4 a = src[u];
        int kb = c2 + u*8;
        wT[(kb+0)*136+orow] = (u16)a.x;  wT[(kb+1)*136+orow] = (u16)(a.x>>16);
        wT[(kb+2)*136+orow] = (u16)a.y;  wT[(kb+3)*136+orow] = (u16)(a.y>>16);
        wT[(kb+4)*136+orow] = (u16)a.z;  wT[(kb+5)*136+orow] = (u16)(a.z>>16);
        wT[(kb+6)*136+orow] = (u16)a.w;  wT[(kb+7)*136+orow] = (u16)(a.w>>16);
      }
    }
  }
  __syncthreads();
  const int tg = tid & 15, og = tid >> 4;
  const int t0 = tg*4, o0 = og*8;
  float acc[4][8];
  #pragma unroll
  for (int j2=0;j2<4;++j2)
    #pragma unroll
    for (int i2=0;i2<8;++i2) acc[j2][i2] = 0.f;
  for (int k=0;k<128;++k){
    ushort4 xa = *(const ushort4*)&xT[k*72 + t0];
    uint4   wb = *(const uint4*)  &wT[k*136 + o0];
    float xv[4] = { b2f(xa.x), b2f(xa.y), b2f(xa.z), b2f(xa.w) };
    float wv[8];
    wv[0]=__uint_as_float(wb.x<<16); wv[1]=__uint_as_float(wb.x&0xffff0000u);
    wv[2]=__uint_as_float(wb.y<<16); wv[3]=__uint_as_float(wb.y&0xffff0000u);
    wv[4]=__uint_as_float(wb.z<<16); wv[5]=__uint_as_float(wb.z&0xffff0000u);
    wv[6]=__uint_as_float(wb.w<<16); wv[7]=__uint_as_float(wb.w&0xffff0000u);
    #pragma unroll
    for (int j2=0;j2<4;++j2)
      #pragma unroll
      for (int i2=0;i2<8;++i2) acc[j2][i2] = fmaf(xv[j2], wv[i2], acc[j2][i2]);
  }
  float bv[8];
  #pragma unroll
  for (int i2=0;i2<8;++i2) bv[i2] = ldf(pb, o0+i2, isf32);
  #pragma unroll
  for (int j2=0;j2<4;++j2){
    int g = g0 + t0 + j2;
    int win = g/392, tt = g - win*392;
    int dwi = win>>6, hwi = (win>>3)&7, wwi = win&7;
    int td = tt/49; int r2 = tt - td*49; int th = r2/7; int tw = r2 - th*7;
    int pd = dwi*8 + td + 4; if (pd >= 16) pd -= 16;
    int ph = hwi*7 + th + 3; if (ph >= 56) ph -= 56;
    int pwx = wwi*7 + tw + 3; if (pwx >= 56) pwx -= 56;
    size_t pos = (size_t)((pd*56 + ph)*56 + pwx)*128 + o0;
    if (isf32){
      float* dst = (float*)out + pos;
      float4 lo4 = make_float4(acc[j2][0]+bv[0], acc[j2][1]+bv[1],
                               acc[j2][2]+bv[2], acc[j2][3]+bv[3]);
      float4 hi4 = make_float4(acc[j2][4]+bv[4], acc[j2][5]+bv[5],
                               acc[j2][6]+bv[6], acc[j2][7]+bv[7]);
      *(float4*)dst = lo4;
      *(float4*)(dst+4) = hi4;
    } else {
      u16* dst = (u16*)out + pos;
      uint4 val;
      val.x = (u32)f2b(acc[j2][0]+bv[0]) | ((u32)f2b(acc[j2][1]+bv[1])<<16);
      val.y = (u32)f2b(acc[j2][2]+bv[2]) | ((u32)f2b(acc[j2][3]+bv[3])<<16);
      val.z = (u32)f2b(acc[j2][4]+bv[4]) | ((u32)f2b(acc[j2][5]+bv[5])<<16);
      val.w = (u32)f2b(acc[j2][6]+bv[6]) | ((u32)f2b(acc[j2][7]+bv[7])<<16);
      *(uint4*)dst = val;
    }
  }
}

extern "C" void kernel_launch(void* const* d_in, const int* in_sizes, int n_in,
                              void* d_out, int out_size, void* d_ws, size_t ws_size,
                              hipStream_t stream){
  const void* x      = d_in[0];
  const void* qkv_w  = d_in[1];
  const void* qkv_b  = d_in[2];
  const void* proj_w = d_in[3];
  const void* proj_b = d_in[4];
  const void* lsc    = d_in[5];
  const void* cpb_w1 = d_in[6];
  const void* cpb_b1 = d_in[7];
  const void* cpb_w2 = d_in[8];
  char* ws = (char*)d_ws;
  int*   flag    = (int*)(ws);                               // 256 B
  float* table16 = (float*)(ws + 256);                       // 40,960 B
  float* bias16  = (float*)(ws + 256 + 40960);               // 2,458,624 B
  u16*   qkvbuf  = (u16*)(ws + 256 + 40960 + 2458624);       // 38,535,168 B
  u16*   attnout = (u16*)(ws + 256 + 40960 + 2458624 + 38535168); // 12,845,056 B

  k_detect<<<1, 256, 0, stream>>>((const u32*)x, flag);
  k_cpb <<<TBL, 64, 0, stream>>>(cpb_w1, cpb_b1, cpb_w2, flag, table16);
  k_bias<<<dim3(392,4), 128, 0, stream>>>(table16, bias16);
  k_qkv <<<dim3(784,3), 256, 0, stream>>>(x, qkv_w, qkv_b, flag, qkvbuf);
  k_attn<<<dim3(128,4), 256, 0, stream>>>(qkvbuf, bias16, lsc, flag, attnout);
  k_proj<<<784, 256, 0, stream>>>(attnout, proj_w, proj_b, flag, d_out);
}

// Round 3
// 166.097 us; speedup vs baseline: 4.0136x; 4.0136x over previous
//
#include <hip/hip_runtime.h>
#include <hip/hip_bf16.h>

typedef unsigned short u16;
typedef unsigned int   u32;
typedef float f32x4  __attribute__((ext_vector_type(4)));
typedef short bf16x8 __attribute__((ext_vector_type(8)));

#define DI __device__ __forceinline__

constexpr int TBL  = 2535;     // (2*8-1)*(2*7-1)*(2*7-1)
constexpr int NTOK = 50176;    // 128 windows * 392 tokens

DI float b2f(u16 u){ return __uint_as_float(((u32)u)<<16); }
DI u16 f2b(float f){
  u32 u = __float_as_uint(f);
  return (u16)((u + 0x7fffu + ((u>>16)&1u)) >> 16);
}
DI float ldf(const void* p, int i, int isf32){
  return isf32 ? ((const float*)p)[i] : b2f(((const u16*)p)[i]);
}
DI f32x4 mfma16(bf16x8 a, bf16x8 b, f32x4 c){
  return __builtin_amdgcn_mfma_f32_16x16x32_bf16(a, b, c, 0, 0, 0);
}

// ---------------- 0) dtype detector (f32 vs bf16 input buffers)
__global__ void k_detect(const u32* __restrict__ xw, int* __restrict__ flag){
  __shared__ int cnt;
  if (threadIdx.x == 0) cnt = 0;
  __syncthreads();
  int local = 0;
  for (int k = threadIdx.x; k < 4096; k += 256){
    u32 w = xw[k];
    u16 lo = (u16)w;
    u32 e = (lo >> 7) & 0xFF;
    if (lo != 0 && (e >= 143 || e <= 111)) local++;
  }
  atomicAdd(&cnt, local);
  __syncthreads();
  if (threadIdx.x == 0) *flag = (cnt > 1000) ? 1 : 0;
}

// ---------------- 1) CPB MLP table
__global__ void k_cpb(const void* __restrict__ w1, const void* __restrict__ b1,
                      const void* __restrict__ w2, const int* __restrict__ flag,
                      float* __restrict__ table16){
  const int isf32 = *flag;
  int t = blockIdx.x, lane = threadIdx.x;
  int i = t/169; int r = t - i*169; int j = r/13; int k = r - j*13;
  float v0 = 8.f*(float)(i-7)/7.f, v1 = 8.f*(float)(j-6)/6.f, v2 = 8.f*(float)(k-6)/6.f;
  float c0 = copysignf(log2f(fabsf(v0)+1.f)*(1.f/3.f), v0);
  float c1 = copysignf(log2f(fabsf(v1)+1.f)*(1.f/3.f), v1);
  float c2 = copysignf(log2f(fabsf(v2)+1.f)*(1.f/3.f), v2);
  float a0=0.f,a1=0.f,a2=0.f,a3=0.f;
  for (int hh = lane; hh < 512; hh += 64){
    float a = c0*ldf(w1,hh*3,isf32) + c1*ldf(w1,hh*3+1,isf32)
            + c2*ldf(w1,hh*3+2,isf32) + ldf(b1,hh,isf32);
    a = fmaxf(a, 0.f);
    a0 += a*ldf(w2,hh,isf32);       a1 += a*ldf(w2,512+hh,isf32);
    a2 += a*ldf(w2,1024+hh,isf32);  a3 += a*ldf(w2,1536+hh,isf32);
  }
  #pragma unroll
  for (int off=32; off; off>>=1){
    a0 += __shfl_xor(a0, off); a1 += __shfl_xor(a1, off);
    a2 += __shfl_xor(a2, off); a3 += __shfl_xor(a3, off);
  }
  if (lane==0){
    table16[t]       = 16.f/(1.f+__expf(-a0));
    table16[TBL+t]   = 16.f/(1.f+__expf(-a1));
    table16[2*TBL+t] = 16.f/(1.f+__expf(-a2));
    table16[3*TBL+t] = 16.f/(1.f+__expf(-a3));
  }
}

// ---------------- 2) expand to bias16[h][n][m]
__global__ void k_bias(const float* __restrict__ table16, float* __restrict__ bias16){
  int n = blockIdx.x, h = blockIdx.y;
  int td = n/49; int r2 = n - td*49; int th = r2/7; int tw = r2 - th*7;
  const float* tb = table16 + h*TBL;
  float* o = bias16 + ((size_t)h*392 + n)*392;
  for (int m = threadIdx.x; m < 392; m += 128){
    int sd = m/49; int q2 = m - sd*49; int sh = q2/7; int sw = q2 - sh*7;
    int idx = (td - sd + 7)*169 + (th - sh + 6)*13 + (tw - sw + 6);
    o[m] = tb[idx];
  }
}

// ---------------- 3) QKV GEMM via MFMA (roll + window partition fused in gather)
// grid (784, 3): 64 tokens x 128 oc; wave owns 16 tokens x 8 n-tiles, K=128.
__global__ __launch_bounds__(256,2) void k_qkv(const void* __restrict__ x,
    const void* __restrict__ qw, const void* __restrict__ qb,
    const int* __restrict__ flag, u16* __restrict__ qkvbuf){
  __shared__ __align__(16) u16 As[64*136];   // [tok][k], stride 136
  __shared__ __align__(16) u16 Ws[128*136];  // [oc][k]
  const int isf32 = *flag;
  const int tid = threadIdx.x;
  const int which = blockIdx.y;
  const int tokbase0 = blockIdx.x*64;
  { // stage x rows (gather through roll+window mapping), row-major
    int trow = tid>>2, cq = (tid&3)*32;
    int gtok = tokbase0 + trow;
    int win = gtok/392, tt = gtok - win*392;
    int dwi = win>>6, hwi = (win>>3)&7, wwi = win&7;
    int td = tt/49; int r2 = tt - td*49; int th = r2/7; int tw = r2 - th*7;
    int pd = dwi*8 + td + 4; if (pd >= 16) pd -= 16;
    int ph = hwi*7 + th + 3; if (ph >= 56) ph -= 56;
    int pw = wwi*7 + tw + 3; if (pw >= 56) pw -= 56;
    size_t pos = (size_t)((pd*56 + ph)*56 + pw)*128 + cq;
    if (isf32){
      const float4* src = (const float4*)((const float*)x + pos);
      #pragma unroll
      for (int u=0; u<8; ++u){
        float4 a = src[u];
        ushort4 s4 = make_ushort4(f2b(a.x), f2b(a.y), f2b(a.z), f2b(a.w));
        *(ushort4*)&As[trow*136 + cq + u*4] = s4;
      }
    } else {
      const uint4* src = (const uint4*)((const u16*)x + pos);
      #pragma unroll
      for (int u=0; u<4; ++u) *(uint4*)&As[trow*136 + cq + u*8] = src[u];
    }
  }
  { // stage weight rows [which*128 .. +127], row-major
    int orow = tid>>1, c2 = (tid&1)*64;
    size_t pos = (size_t)(which*128 + orow)*128 + c2;
    if (isf32){
      const float4* src = (const float4*)((const float*)qw + pos);
      #pragma unroll
      for (int u=0; u<16; ++u){
        float4 a = src[u];
        ushort4 s4 = make_ushort4(f2b(a.x), f2b(a.y), f2b(a.z), f2b(a.w));
        *(ushort4*)&Ws[orow*136 + c2 + u*4] = s4;
      }
    } else {
      const uint4* src = (const uint4*)((const u16*)qw + pos);
      #pragma unroll
      for (int u=0; u<8; ++u) *(uint4*)&Ws[orow*136 + c2 + u*8] = src[u];
    }
  }
  __syncthreads();
  const int wave = tid>>6, lane = tid&63;
  const int c = lane & 15, g = lane >> 4;
  bf16x8 ka[4];
  #pragma unroll
  for (int kk=0; kk<4; ++kk)
    ka[kk] = *(const bf16x8*)&As[(wave*16 + c)*136 + kk*32 + g*8];
  f32x4 acc[8];
  #pragma unroll
  for (int nt=0; nt<8; ++nt) acc[nt] = 0.f;
  #pragma unroll
  for (int nt=0; nt<8; ++nt){
    #pragma unroll
    for (int kk=0; kk<4; ++kk){
      bf16x8 wb = *(const bf16x8*)&Ws[(nt*16 + c)*136 + kk*32 + g*8];
      acc[nt] = mfma16(ka[kk], wb, acc[nt]);
    }
  }
  const int tokbase = tokbase0 + wave*16;
  #pragma unroll
  for (int nt=0; nt<8; ++nt){
    int oc = nt*16 + c;
    float bv = (which==1) ? 0.f : ldf(qb, which*128 + oc, isf32);  // k-bias zeroed
    int head = oc >> 5, chb = oc & 31;
    #pragma unroll
    for (int r=0;r<4;++r){
      int t = tokbase + 4*g + r;
      qkvbuf[((size_t)(which*4+head)*NTOK + t)*32 + chb] = f2b(acc[nt][r] + bv);
    }
  }
}

// ---------------- 4) attention via MFMA: one block per (window, head)
__global__ __launch_bounds__(256,1) void k_attn(const u16* __restrict__ qkv,
    const float* __restrict__ bias16, const void* __restrict__ lsc,
    const int* __restrict__ flag, u16* __restrict__ aout){
  __shared__ __align__(16) u16 klds[400*40];      // 32000 B [tok][k], stride 40
  __shared__ __align__(16) u16 vT[32*424];        // 27136 B [ch][m],  stride 424
  __shared__ __align__(16) u16 plds[4*16*424];    // 54272 B per-wave P [16][424]
  __shared__ float qsl[400];
  __shared__ float kinv[400];
  __shared__ int   cntk[400];
  const int isf32 = *flag;
  const int tid = threadIdx.x;
  const int win = blockIdx.x, h = blockIdx.y;
  const int dwi = win>>6, hwi = (win>>3)&7, wwi = win&7;
  const u16* qg = qkv + ((size_t)(0*4 + h)*NTOK + (size_t)win*392)*32;
  const u16* kg = qkv + ((size_t)(1*4 + h)*NTOK + (size_t)win*392)*32;
  const u16* vg = qkv + ((size_t)(2*4 + h)*NTOK + (size_t)win*392)*32;
  // stage K rows + V transposed
  for (int idx = tid; idx < 1568; idx += 256){
    int m = idx>>2, cq = idx&3;
    uint4 a = ((const uint4*)kg)[idx];
    *(uint4*)&klds[m*40 + cq*8] = a;
    uint4 b = ((const uint4*)vg)[idx];
    int ch = cq*8;
    vT[(ch+0)*424 + m] = (u16)b.x;  vT[(ch+1)*424 + m] = (u16)(b.x>>16);
    vT[(ch+2)*424 + m] = (u16)b.y;  vT[(ch+3)*424 + m] = (u16)(b.y>>16);
    vT[(ch+4)*424 + m] = (u16)b.z;  vT[(ch+5)*424 + m] = (u16)(b.z>>16);
    vT[(ch+6)*424 + m] = (u16)b.w;  vT[(ch+7)*424 + m] = (u16)(b.w>>16);
  }
  // zero pads (avoid NaN poisoning in MFMA)
  for (int idx = tid; idx < 320; idx += 256) klds[392*40 + idx] = 0;
  for (int idx = tid; idx < 1024; idx += 256){
    int ch = idx >> 5, mm = 392 + (idx & 31);
    vT[ch*424 + mm] = 0;
  }
  for (int idx = tid; idx < 1536; idx += 256){
    int w = idx / 384; int rem = idx - w*384; int rr = rem / 24; int cc = 400 + rem % 24;
    plds[w*16*424 + rr*424 + cc] = 0;
  }
  // per-row norms, region ids
  const float ls = isf32 ? ((const float*)lsc)[h] : b2f(((const u16*)lsc)[h]);
  const float scale = __expf(fminf(ls, 4.60517019f));
  for (int i = tid; i < 400; i += 256){
    int row = (i < 392) ? i : 391;
    const uint4* qp = (const uint4*)(qg + (size_t)row*32);
    const uint4* kp = (const uint4*)(kg + (size_t)row*32);
    float ssq = 0.f, ssk = 0.f;
    #pragma unroll
    for (int u=0; u<4; ++u){
      uint4 qa = qp[u], kb = kp[u];
      float f;
      f=__uint_as_float(qa.x<<16); ssq+=f*f; f=__uint_as_float(qa.x&0xffff0000u); ssq+=f*f;
      f=__uint_as_float(qa.y<<16); ssq+=f*f; f=__uint_as_float(qa.y&0xffff0000u); ssq+=f*f;
      f=__uint_as_float(qa.z<<16); ssq+=f*f; f=__uint_as_float(qa.z&0xffff0000u); ssq+=f*f;
      f=__uint_as_float(qa.w<<16); ssq+=f*f; f=__uint_as_float(qa.w&0xffff0000u); ssq+=f*f;
      f=__uint_as_float(kb.x<<16); ssk+=f*f; f=__uint_as_float(kb.x&0xffff0000u); ssk+=f*f;
      f=__uint_as_float(kb.y<<16); ssk+=f*f; f=__uint_as_float(kb.y&0xffff0000u); ssk+=f*f;
      f=__uint_as_float(kb.z<<16); ssk+=f*f; f=__uint_as_float(kb.z&0xffff0000u); ssk+=f*f;
      f=__uint_as_float(kb.w<<16); ssk+=f*f; f=__uint_as_float(kb.w&0xffff0000u); ssk+=f*f;
    }
    qsl[i]  = scale / fmaxf(sqrtf(ssq), 1e-12f);
    kinv[i] = 1.f   / fmaxf(sqrtf(ssk), 1e-12f);
    int td = row/49; int r2 = row - td*49; int th = r2/7; int tw = r2 - th*7;
    int gd = dwi*8 + td, gh = hwi*7 + th, gw = wwi*7 + tw;
    int rd = (gd < 8) ? 0 : ((gd < 12) ? 1 : 2);
    int rh = (gh < 49) ? 0 : ((gh < 53) ? 1 : 2);
    int rw = (gw < 49) ? 0 : ((gw < 53) ? 1 : 2);
    cntk[i] = (i < 392) ? (rd*9 + rh*3 + rw) : -1;
  }
  __syncthreads();

  const int wave = tid>>6, lane = tid&63;
  const int c = lane & 15, g = lane >> 4;
  const float* bias_h = bias16 + (size_t)h*392*392;
  u16* Pw = plds + wave*16*424;

  for (int rt = wave; rt < 25; rt += 4){
    // Q A-fragment (one 16B global load)
    int qrow = rt*16 + c; if (qrow > 391) qrow = 391;
    bf16x8 qa = *(const bf16x8*)(qg + (size_t)qrow*32 + g*8);
    // QK^T: 25 j-tiles
    f32x4 acc[25];
    #pragma unroll
    for (int jt=0; jt<25; ++jt){
      bf16x8 kb = *(const bf16x8*)&klds[(jt*16 + c)*40 + g*8];
      f32x4 z = 0.f;
      acc[jt] = mfma16(qa, kb, z);
    }
    // fixup: cosine norm * scale + bias + shift mask; track row max
    const int nbase = rt*16 + 4*g;
    float qsr[4]; int cnr[4]; const float* bp[4];
    #pragma unroll
    for (int r=0;r<4;++r){
      int n = nbase + r;
      qsr[r] = qsl[n];
      cnr[r] = cntk[n];
      bp[r]  = bias_h + (size_t)((n < 392) ? n : 391)*392;
    }
    float mx[4] = {-1e30f,-1e30f,-1e30f,-1e30f};
    #pragma unroll
    for (int jt=0; jt<25; ++jt){
      int m = jt*16 + c;
      float kv = kinv[m];
      int   cm = cntk[m];
      bool valid = (m < 392);
      #pragma unroll
      for (int r=0;r<4;++r){
        float b = valid ? bp[r][m] : 0.f;
        float s = fmaf(acc[jt][r], kv*qsr[r], b);
        s += (cm == cnr[r]) ? 0.f : -100.f;
        if (!valid) s = -1e30f;
        acc[jt][r] = s;
        mx[r] = fmaxf(mx[r], s);
      }
    }
    #pragma unroll
    for (int r=0;r<4;++r){
      #pragma unroll
      for (int off=1; off<16; off<<=1) mx[r] = fmaxf(mx[r], __shfl_xor(mx[r], off));
    }
    float sm[4] = {0.f,0.f,0.f,0.f};
    #pragma unroll
    for (int jt=0; jt<25; ++jt){
      #pragma unroll
      for (int r=0;r<4;++r){
        float p = __expf(acc[jt][r] - mx[r]);
        acc[jt][r] = p;
        sm[r] += p;
      }
    }
    #pragma unroll
    for (int r=0;r<4;++r){
      #pragma unroll
      for (int off=1; off<16; off<<=1) sm[r] += __shfl_xor(sm[r], off);
      sm[r] = 1.f / sm[r];
    }
    // write unnormalized P (bf16) to per-wave LDS
    #pragma unroll
    for (int jt=0; jt<25; ++jt){
      int col = jt*16 + c;
      #pragma unroll
      for (int r=0;r<4;++r)
        Pw[(4*g + r)*424 + col] = f2b(acc[jt][r]);
    }
    // PV: 13 m-chunks x 2 channel tiles
    f32x4 o0 = 0.f, o1 = 0.f;
    #pragma unroll
    for (int mc=0; mc<13; ++mc){
      bf16x8 pa  = *(const bf16x8*)&Pw[c*424 + mc*32 + g*8];
      bf16x8 vb0 = *(const bf16x8*)&vT[c*424 + mc*32 + g*8];
      bf16x8 vb1 = *(const bf16x8*)&vT[(16+c)*424 + mc*32 + g*8];
      o0 = mfma16(pa, vb0, o0);
      o1 = mfma16(pa, vb1, o1);
    }
    // store normalized O
    #pragma unroll
    for (int r=0;r<4;++r){
      int n = nbase + r;
      if (n < 392){
        size_t base = ((size_t)(win*392 + n))*128 + h*32;
        aout[base + c]      = f2b(o0[r] * sm[r]);
        aout[base + 16 + c] = f2b(o1[r] * sm[r]);
      }
    }
  }
}

// ---------------- 5) projection GEMM via MFMA + window reverse + roll-back
__global__ __launch_bounds__(256,2) void k_proj(const u16* __restrict__ ain,
    const void* __restrict__ pwt, const void* __restrict__ pb,
    const int* __restrict__ flag, void* __restrict__ out){
  __shared__ __align__(16) u16 As[64*136];
  __shared__ __align__(16) u16 Ws[128*136];
  const int isf32 = *flag;
  const int tid = threadIdx.x;
  const int tokbase0 = blockIdx.x*64;
  { // stage attn-out rows (always bf16)
    int trow = tid>>2, cq = (tid&3)*32;
    const uint4* src = (const uint4*)(ain + (size_t)(tokbase0+trow)*128 + cq);
    #pragma unroll
    for (int u=0; u<4; ++u) *(uint4*)&As[trow*136 + cq + u*8] = src[u];
  }
  { // stage proj weights
    int orow = tid>>1, c2 = (tid&1)*64;
    size_t pos = (size_t)orow*128 + c2;
    if (isf32){
      const float4* src = (const float4*)((const float*)pwt + pos);
      #pragma unroll
      for (int u=0; u<16; ++u){
        float4 a = src[u];
        ushort4 s4 = make_ushort4(f2b(a.x), f2b(a.y), f2b(a.z), f2b(a.w));
        *(ushort4*)&Ws[orow*136 + c2 + u*4] = s4;
      }
    } else {
      const uint4* src = (const uint4*)((const u16*)pwt + pos);
      #pragma unroll
      for (int u=0; u<8; ++u) *(uint4*)&Ws[orow*136 + c2 + u*8] = src[u];
    }
  }
  __syncthreads();
  const int wave = tid>>6, lane = tid&63;
  const int c = lane & 15, g = lane >> 4;
  bf16x8 ka[4];
  #pragma unroll
  for (int kk=0; kk<4; ++kk)
    ka[kk] = *(const bf16x8*)&As[(wave*16 + c)*136 + kk*32 + g*8];
  f32x4 acc[8];
  #pragma unroll
  for (int nt=0; nt<8; ++nt) acc[nt] = 0.f;
  #pragma unroll
  for (int nt=0; nt<8; ++nt){
    #pragma unroll
    for (int kk=0; kk<4; ++kk){
      bf16x8 wb = *(const bf16x8*)&Ws[(nt*16 + c)*136 + kk*32 + g*8];
      acc[nt] = mfma16(ka[kk], wb, acc[nt]);
    }
  }
  // per-r output position (window reverse + roll-back)
  const int tokbase = tokbase0 + wave*16;
  size_t po[4];
  #pragma unroll
  for (int r=0;r<4;++r){
    int gtok = tokbase + 4*g + r;
    int win = gtok/392, tt = gtok - win*392;
    int dwi = win>>6, hwi = (win>>3)&7, wwi = win&7;
    int td = tt/49; int r2 = tt - td*49; int th = r2/7; int tw = r2 - th*7;
    int pd = dwi*8 + td + 4; if (pd >= 16) pd -= 16;
    int ph = hwi*7 + th + 3; if (ph >= 56) ph -= 56;
    int pwx = wwi*7 + tw + 3; if (pwx >= 56) pwx -= 56;
    po[r] = (size_t)((pd*56 + ph)*56 + pwx)*128;
  }
  #pragma unroll
  for (int nt=0; nt<8; ++nt){
    int oc = nt*16 + c;
    float bv = ldf(pb, oc, isf32);
    #pragma unroll
    for (int r=0;r<4;++r){
      float v = acc[nt][r] + bv;
      if (isf32) ((float*)out)[po[r] + oc] = v;
      else       ((u16*)out)[po[r] + oc] = f2b(v);
    }
  }
}

extern "C" void kernel_launch(void* const* d_in, const int* in_sizes, int n_in,
                              void* d_out, int out_size, void* d_ws, size_t ws_size,
                              hipStream_t stream){
  const void* x      = d_in[0];
  const void* qkv_w  = d_in[1];
  const void* qkv_b  = d_in[2];
  const void* proj_w = d_in[3];
  const void* proj_b = d_in[4];
  const void* lsc    = d_in[5];
  const void* cpb_w1 = d_in[6];
  const void* cpb_b1 = d_in[7];
  const void* cpb_w2 = d_in[8];
  char* ws = (char*)d_ws;
  int*   flag    = (int*)(ws);                               // 256 B
  float* table16 = (float*)(ws + 256);                       // 40,960 B
  float* bias16  = (float*)(ws + 256 + 40960);               // 2,458,624 B
  u16*   qkvbuf  = (u16*)(ws + 256 + 40960 + 2458624);       // 38,535,168 B
  u16*   attnout = (u16*)(ws + 256 + 40960 + 2458624 + 38535168); // 12,845,056 B

  k_detect<<<1, 256, 0, stream>>>((const u32*)x, flag);
  k_cpb <<<TBL, 64, 0, stream>>>(cpb_w1, cpb_b1, cpb_w2, flag, table16);
  k_bias<<<dim3(392,4), 128, 0, stream>>>(table16, bias16);
  k_qkv <<<dim3(784,3), 256, 0, stream>>>(x, qkv_w, qkv_b, flag, qkvbuf);
  k_attn<<<dim3(128,4), 256, 0, stream>>>(qkvbuf, bias16, lsc, flag, attnout);
  k_proj<<<784, 256, 0, stream>>>(attnout, proj_w, proj_b, flag, d_out);
}

// Round 4
// 102.585 us; speedup vs baseline: 6.4985x; 1.6191x over previous
//
#include <hip/hip_runtime.h>
#include <hip/hip_bf16.h>

typedef unsigned short u16;
typedef unsigned int   u32;
typedef float f32x4  __attribute__((ext_vector_type(4)));
typedef short bf16x8 __attribute__((ext_vector_type(8)));

#define DI __device__ __forceinline__

constexpr int TBL  = 2535;     // (2*8-1)*(2*7-1)*(2*7-1)
constexpr int NTOK = 50176;    // 128 windows * 392 tokens

// bf16 weight scratch layout (u16 units)
constexpr int WB_QW = 0;          // 49152
constexpr int WB_PW = 49152;      // 16384
constexpr int WB_QB = 65536;      // 384
constexpr int WB_PB = 65920;      // 128
constexpr int WB_TOT = 66048;

DI float b2f(u16 u){ return __uint_as_float(((u32)u)<<16); }
DI u16 f2b(float f){
  u32 u = __float_as_uint(f);
  return (u16)((u + 0x7fffu + ((u>>16)&1u)) >> 16);
}
DI float ldf(const void* p, int i, int isf32){
  return isf32 ? ((const float*)p)[i] : b2f(((const u16*)p)[i]);
}
DI f32x4 mfma16(bf16x8 a, bf16x8 b, f32x4 c){
  return __builtin_amdgcn_mfma_f32_16x16x32_bf16(a, b, c, 0, 0, 0);
}
DI u32 cvtpk(float lo, float hi){
  u32 r;
  asm("v_cvt_pk_bf16_f32 %0, %1, %2" : "=v"(r) : "v"(lo), "v"(hi));
  return r;
}
DI float ssq8(uint4 a){
  float s = 0.f, f;
  f=__uint_as_float(a.x<<16); s+=f*f; f=__uint_as_float(a.x&0xffff0000u); s+=f*f;
  f=__uint_as_float(a.y<<16); s+=f*f; f=__uint_as_float(a.y&0xffff0000u); s+=f*f;
  f=__uint_as_float(a.z<<16); s+=f*f; f=__uint_as_float(a.z&0xffff0000u); s+=f*f;
  f=__uint_as_float(a.w<<16); s+=f*f; f=__uint_as_float(a.w&0xffff0000u); s+=f*f;
  return s;
}

// ---------------- 0) dtype detector (f32 vs bf16 input buffers)
__global__ void k_detect(const u32* __restrict__ xw, int* __restrict__ flag){
  __shared__ int cnt;
  if (threadIdx.x == 0) cnt = 0;
  __syncthreads();
  int local = 0;
  for (int k = threadIdx.x; k < 4096; k += 256){
    u32 w = xw[k];
    u16 lo = (u16)w;
    u32 e = (lo >> 7) & 0xFF;
    if (lo != 0 && (e >= 143 || e <= 111)) local++;
  }
  atomicAdd(&cnt, local);
  __syncthreads();
  if (threadIdx.x == 0) *flag = (cnt > 1000) ? 1 : 0;
}

// ---------------- 0b) convert weights/biases to bf16 scratch
__global__ void k_wconv(const void* __restrict__ qw, const void* __restrict__ pw,
                        const void* __restrict__ qb, const void* __restrict__ pb,
                        const int* __restrict__ flag, u16* __restrict__ wb){
  const int isf32 = *flag;
  int i = blockIdx.x*256 + threadIdx.x;
  if (i >= WB_TOT) return;
  const void* src; int off;
  if (i < WB_PW)      { src = qw; off = i; }
  else if (i < WB_QB) { src = pw; off = i - WB_PW; }
  else if (i < WB_PB) { src = qb; off = i - WB_QB; }
  else                { src = pb; off = i - WB_PB; }
  wb[i] = isf32 ? f2b(((const float*)src)[off]) : ((const u16*)src)[off];
}

// ---------------- 1) CPB MLP table
__global__ void k_cpb(const void* __restrict__ w1, const void* __restrict__ b1,
                      const void* __restrict__ w2, const int* __restrict__ flag,
                      float* __restrict__ table16){
  const int isf32 = *flag;
  int t = blockIdx.x, lane = threadIdx.x;
  int i = t/169; int r = t - i*169; int j = r/13; int k = r - j*13;
  float v0 = 8.f*(float)(i-7)/7.f, v1 = 8.f*(float)(j-6)/6.f, v2 = 8.f*(float)(k-6)/6.f;
  float c0 = copysignf(log2f(fabsf(v0)+1.f)*(1.f/3.f), v0);
  float c1 = copysignf(log2f(fabsf(v1)+1.f)*(1.f/3.f), v1);
  float c2 = copysignf(log2f(fabsf(v2)+1.f)*(1.f/3.f), v2);
  float a0=0.f,a1=0.f,a2=0.f,a3=0.f;
  for (int hh = lane; hh < 512; hh += 64){
    float a = c0*ldf(w1,hh*3,isf32) + c1*ldf(w1,hh*3+1,isf32)
            + c2*ldf(w1,hh*3+2,isf32) + ldf(b1,hh,isf32);
    a = fmaxf(a, 0.f);
    a0 += a*ldf(w2,hh,isf32);       a1 += a*ldf(w2,512+hh,isf32);
    a2 += a*ldf(w2,1024+hh,isf32);  a3 += a*ldf(w2,1536+hh,isf32);
  }
  #pragma unroll
  for (int off=32; off; off>>=1){
    a0 += __shfl_xor(a0, off); a1 += __shfl_xor(a1, off);
    a2 += __shfl_xor(a2, off); a3 += __shfl_xor(a3, off);
  }
  if (lane==0){
    table16[t]       = 16.f/(1.f+__expf(-a0));
    table16[TBL+t]   = 16.f/(1.f+__expf(-a1));
    table16[2*TBL+t] = 16.f/(1.f+__expf(-a2));
    table16[3*TBL+t] = 16.f/(1.f+__expf(-a3));
  }
}

// ---------------- 2) expand to bias16[h][n][m]
__global__ void k_bias(const float* __restrict__ table16, float* __restrict__ bias16){
  int n = blockIdx.x, h = blockIdx.y;
  int td = n/49; int r2 = n - td*49; int th = r2/7; int tw = r2 - th*7;
  const float* tb = table16 + h*TBL;
  float* o = bias16 + ((size_t)h*392 + n)*392;
  for (int m = threadIdx.x; m < 392; m += 128){
    int sd = m/49; int q2 = m - sd*49; int sh = q2/7; int sw = q2 - sh*7;
    int idx = (td - sd + 7)*169 + (th - sh + 6)*13 + (tw - sw + 6);
    o[m] = tb[idx];
  }
}

// ---------------- 3) QKV GEMM via MFMA, all three of q/k/v per block
__global__ __launch_bounds__(256,3) void k_qkv(const void* __restrict__ x,
    const u16* __restrict__ wb, const int* __restrict__ flag, u16* __restrict__ qkvbuf){
  __shared__ __align__(16) u16 As[64*136];   // [tok][k], stride 136
  __shared__ __align__(16) u16 Ws[128*136];  // [oc][k]
  const int isf32 = *flag;
  const int tid = threadIdx.x;
  const int tokbase0 = blockIdx.x*64;
  { // stage x rows (gather through roll+window mapping)
    int trow = tid>>2, cq = (tid&3)*32;
    int gtok = tokbase0 + trow;
    int win = gtok/392, tt = gtok - win*392;
    int dwi = win>>6, hwi = (win>>3)&7, wwi = win&7;
    int td = tt/49; int r2 = tt - td*49; int th = r2/7; int tw = r2 - th*7;
    int pd = dwi*8 + td + 4; if (pd >= 16) pd -= 16;
    int ph = hwi*7 + th + 3; if (ph >= 56) ph -= 56;
    int pw = wwi*7 + tw + 3; if (pw >= 56) pw -= 56;
    size_t pos = (size_t)((pd*56 + ph)*56 + pw)*128 + cq;
    if (isf32){
      const float4* src = (const float4*)((const float*)x + pos);
      #pragma unroll
      for (int u=0; u<8; ++u){
        float4 a = src[u];
        ushort4 s4 = make_ushort4(f2b(a.x), f2b(a.y), f2b(a.z), f2b(a.w));
        *(ushort4*)&As[trow*136 + cq + u*4] = s4;
      }
    } else {
      const uint4* src = (const uint4*)((const u16*)x + pos);
      #pragma unroll
      for (int u=0; u<4; ++u) *(uint4*)&As[trow*136 + cq + u*8] = src[u];
    }
  }
  const int wave = tid>>6, lane = tid&63;
  const int c = lane & 15, g = lane >> 4;
  const int tokbase = tokbase0 + wave*16;
  bf16x8 ka[4];
  for (int which = 0; which < 3; ++which){
    __syncthreads();   // As ready (first pass) / prior compute's Ws reads done
    { // stage weight rows [which*128 .. +127] (bf16 preconverted)
      int orow = tid>>1, c2 = (tid&1)*64;
      const uint4* src = (const uint4*)(wb + WB_QW + (size_t)(which*128 + orow)*128 + c2);
      #pragma unroll
      for (int u=0; u<8; ++u) *(uint4*)&Ws[orow*136 + c2 + u*8] = src[u];
    }
    __syncthreads();
    if (which == 0){
      #pragma unroll
      for (int kk=0; kk<4; ++kk)
        ka[kk] = *(const bf16x8*)&As[(wave*16 + c)*136 + kk*32 + g*8];
    }
    f32x4 acc[8];
    #pragma unroll
    for (int nt=0; nt<8; ++nt) acc[nt] = 0.f;
    #pragma unroll
    for (int nt=0; nt<8; ++nt){
      #pragma unroll
      for (int kk=0; kk<4; ++kk){
        bf16x8 wf = *(const bf16x8*)&Ws[(nt*16 + c)*136 + kk*32 + g*8];
        acc[nt] = mfma16(ka[kk], wf, acc[nt]);
      }
    }
    #pragma unroll
    for (int nt=0; nt<8; ++nt){
      int oc = nt*16 + c;
      float bv = (which==1) ? 0.f : b2f(wb[WB_QB + which*128 + oc]);  // k-bias zeroed
      int head = oc >> 5, chb = oc & 31;
      #pragma unroll
      for (int r=0;r<4;++r){
        int t = tokbase + 4*g + r;
        qkvbuf[((size_t)(which*4+head)*NTOK + t)*32 + chb] = f2b(acc[nt][r] + bv);
      }
    }
  }
}

// ---------------- 4) attention via swapped-operand MFMA, streaming softmax
// one block per (window, head), 512 threads = 8 waves, each wave owns 16 Q-columns
#define QKT_STEP(JT, JJ) do { \
  bf16x8 kf = *(const bf16x8*)&klds[((JT)*16 + c)*40 + g*8]; \
  f32x4 tz = {0.f,0.f,0.f,0.f}; \
  f32x4 t = mfma16(kf, qf, tz); \
  const int mb = (JT)*16 + 4*g; \
  const int mbc = (mb <= 388) ? mb : 388; \
  const float4 bq = *(const float4*)(brow + mbc); \
  const int4 cmq = *(const int4*)&cnt[mbc]; \
  float s0 = fmaf(t[0], qsc, bq.x + ((cmq.x==cn) ? -15.f : -115.f)); \
  float s1 = fmaf(t[1], qsc, bq.y + ((cmq.y==cn) ? -15.f : -115.f)); \
  float s2 = fmaf(t[2], qsc, bq.z + ((cmq.z==cn) ? -15.f : -115.f)); \
  float s3 = fmaf(t[3], qsc, bq.w + ((cmq.w==cn) ? -15.f : -115.f)); \
  float p0 = __expf(s0), p1 = __expf(s1), p2 = __expf(s2), p3 = __expf(s3); \
  if (mb > 388){ p0=0.f; p1=0.f; p2=0.f; p3=0.f; } \
  sum += (p0+p1) + (p2+p3); \
  uint2 wv; wv.x = cvtpk(p0,p1); wv.y = cvtpk(p2,p3); \
  *(uint2*)&psw[c*20 + (JJ)*8 + 2*g] = wv; \
} while(0)

#define PV_STEP(MC) do { \
  bf16x8 pf = *(const bf16x8*)&psw[c*20 + 4*g]; \
  bf16x8 va = *(const bf16x8*)&vT[c*424 + (MC)*32 + g*8]; \
  bf16x8 vb = *(const bf16x8*)&vT[(16+c)*424 + (MC)*32 + g*8]; \
  o0 = mfma16(va, pf, o0); \
  o1 = mfma16(vb, pf, o1); \
} while(0)

__global__ __launch_bounds__(512,4) void k_attn(const u16* __restrict__ qkv,
    const float* __restrict__ bias16, const void* __restrict__ lsc,
    const int* __restrict__ flag, u16* __restrict__ aout){
  __shared__ __align__(16) u16 klds[400*40];   // K-hat rows [m][k], stride 40 (32000 B)
  __shared__ __align__(16) u16 vT[32*424];     // V^T [ch][m], stride 424 (27136 B)
  __shared__ __align__(16) u32 ps[8][16*20];   // per-wave P/O scratch (10240 B)
  __shared__ __align__(16) float qs[400];
  __shared__ __align__(16) int   cnt[400];
  const int isf32 = *flag;
  const int tid = threadIdx.x;
  const int win = blockIdx.x, h = blockIdx.y;
  const int dwi = win>>6, hwi = (win>>3)&7, wwi = win&7;
  const u16* qg = qkv + ((size_t)(0*4 + h)*NTOK + (size_t)win*392)*32;
  const u16* kg = qkv + ((size_t)(1*4 + h)*NTOK + (size_t)win*392)*32;
  const u16* vg = qkv + ((size_t)(2*4 + h)*NTOK + (size_t)win*392)*32;
  const float ls = isf32 ? ((const float*)lsc)[h] : b2f(((const u16*)lsc)[h]);
  const float scale = __expf(fminf(ls, 4.60517019f));

  // ---- stage K-hat (row-normalized bf16) + q scales; thread pair = (row, half)
  for (int idx = tid; idx < 800; idx += 512){
    const int row = idx>>1, half = idx&1;
    if (row < 392){
      const uint4* kp = (const uint4*)(kg + (size_t)row*32 + half*16);
      uint4 a = kp[0], b = kp[1];
      float fv[16];
      fv[0] =__uint_as_float(a.x<<16); fv[1] =__uint_as_float(a.x&0xffff0000u);
      fv[2] =__uint_as_float(a.y<<16); fv[3] =__uint_as_float(a.y&0xffff0000u);
      fv[4] =__uint_as_float(a.z<<16); fv[5] =__uint_as_float(a.z&0xffff0000u);
      fv[6] =__uint_as_float(a.w<<16); fv[7] =__uint_as_float(a.w&0xffff0000u);
      fv[8] =__uint_as_float(b.x<<16); fv[9] =__uint_as_float(b.x&0xffff0000u);
      fv[10]=__uint_as_float(b.y<<16); fv[11]=__uint_as_float(b.y&0xffff0000u);
      fv[12]=__uint_as_float(b.z<<16); fv[13]=__uint_as_float(b.z&0xffff0000u);
      fv[14]=__uint_as_float(b.w<<16); fv[15]=__uint_as_float(b.w&0xffff0000u);
      float ss = 0.f;
      #pragma unroll
      for (int e=0;e<16;++e) ss = fmaf(fv[e], fv[e], ss);
      ss += __shfl_xor(ss, 1);
      const float rn = 1.f/fmaxf(sqrtf(ss), 1e-12f);
      u16 ob[16];
      #pragma unroll
      for (int e=0;e<16;++e) ob[e] = f2b(fv[e]*rn);
      uint4 w0, w1;
      w0.x = (u32)ob[0] |((u32)ob[1] <<16); w0.y = (u32)ob[2] |((u32)ob[3] <<16);
      w0.z = (u32)ob[4] |((u32)ob[5] <<16); w0.w = (u32)ob[6] |((u32)ob[7] <<16);
      w1.x = (u32)ob[8] |((u32)ob[9] <<16); w1.y = (u32)ob[10]|((u32)ob[11]<<16);
      w1.z = (u32)ob[12]|((u32)ob[13]<<16); w1.w = (u32)ob[14]|((u32)ob[15]<<16);
      *(uint4*)&klds[row*40 + half*16]     = w0;
      *(uint4*)&klds[row*40 + half*16 + 8] = w1;
      const uint4* qp = (const uint4*)(qg + (size_t)row*32 + half*16);
      float sq = ssq8(qp[0]) + ssq8(qp[1]);
      sq += __shfl_xor(sq, 1);
      if (half == 0) qs[row] = scale / fmaxf(sqrtf(sq), 1e-12f);
    } else {
      uint4 z = {0,0,0,0};
      *(uint4*)&klds[row*40 + half*16]     = z;
      *(uint4*)&klds[row*40 + half*16 + 8] = z;
      if (half == 0) qs[row] = 1.f;
    }
  }
  // ---- region ids
  for (int t2 = tid; t2 < 400; t2 += 512){
    int row = (t2 < 392) ? t2 : 391;
    int td = row/49; int r2 = row - td*49; int th = r2/7; int tw = r2 - th*7;
    int gd = dwi*8 + td, gh = hwi*7 + th, gw = wwi*7 + tw;
    int rd = (gd < 8) ? 0 : ((gd < 12) ? 1 : 2);
    int rh = (gh < 49) ? 0 : ((gh < 53) ? 1 : 2);
    int rw = (gw < 49) ? 0 : ((gw < 53) ? 1 : 2);
    cnt[t2] = rd*9 + rh*3 + rw;
  }
  // ---- stage V transposed
  for (int idx = tid; idx < 1568; idx += 512){
    int m = idx>>2, cq = idx&3;
    uint4 b = ((const uint4*)vg)[idx];
    int ch = cq*8;
    vT[(ch+0)*424 + m] = (u16)b.x;  vT[(ch+1)*424 + m] = (u16)(b.x>>16);
    vT[(ch+2)*424 + m] = (u16)b.y;  vT[(ch+3)*424 + m] = (u16)(b.y>>16);
    vT[(ch+4)*424 + m] = (u16)b.z;  vT[(ch+5)*424 + m] = (u16)(b.z>>16);
    vT[(ch+6)*424 + m] = (u16)b.w;  vT[(ch+7)*424 + m] = (u16)(b.w>>16);
  }
  for (int idx = tid; idx < 1024; idx += 512){
    int ch = idx>>5, mm = 392 + (idx&31);
    vT[ch*424 + mm] = 0;
  }
  __syncthreads();

  const int wave = tid>>6, lane = tid&63;
  const int c = lane & 15, g = lane >> 4;
  u32* psw = &ps[wave][0];
  for (int rt = wave; rt < 25; rt += 8){
    const int nb = rt*16;
    const int nc = (nb + c < 392) ? (nb + c) : 391;
    const bf16x8 qf = *(const bf16x8*)(qg + (size_t)nc*32 + g*8);
    const float qsc = qs[nc];
    const int   cn  = cnt[nc];
    const float* brow = bias16 + (size_t)h*153664 + (size_t)nc*392;
    float sum = 0.f;
    f32x4 o0 = {0.f,0.f,0.f,0.f}, o1 = {0.f,0.f,0.f,0.f};
    for (int mc = 0; mc < 12; ++mc){
      QKT_STEP(2*mc,   0);
      QKT_STEP(2*mc+1, 1);
      PV_STEP(mc);
    }
    QKT_STEP(24, 0);
    { uint2 zz; zz.x = 0u; zz.y = 0u; *(uint2*)&psw[c*20 + 8 + 2*g] = zz; }
    PV_STEP(12);
    // normalize + coalesced store via LDS bounce
    sum += __shfl_xor(sum, 16);
    sum += __shfl_xor(sum, 32);
    const float rv = 1.f/sum;
    uint2 wa, wb2;
    wa.x  = cvtpk(o0[0]*rv, o0[1]*rv);  wa.y  = cvtpk(o0[2]*rv, o0[3]*rv);
    wb2.x = cvtpk(o1[0]*rv, o1[1]*rv);  wb2.y = cvtpk(o1[2]*rv, o1[3]*rv);
    *(uint2*)&psw[c*20 + 2*g]     = wa;
    *(uint2*)&psw[c*20 + 8 + 2*g] = wb2;
    const int orow = lane>>2, oq = lane&3;
    uint4 ov = *(const uint4*)&psw[orow*20 + 4*oq];
    const int n = nb + orow;
    if (n < 392)
      *(uint4*)(aout + ((size_t)(win*392 + n))*128 + h*32 + oq*8) = ov;
  }
}

// ---------------- 5) projection GEMM via MFMA + window reverse + roll-back
__global__ __launch_bounds__(256,2) void k_proj(const u16* __restrict__ ain,
    const u16* __restrict__ wb, const int* __restrict__ flag, void* __restrict__ out){
  __shared__ __align__(16) u16 As[64*136];
  __shared__ __align__(16) u16 Ws[128*136];
  const int isf32 = *flag;
  const int tid = threadIdx.x;
  const int tokbase0 = blockIdx.x*64;
  {
    int trow = tid>>2, cq = (tid&3)*32;
    const uint4* src = (const uint4*)(ain + (size_t)(tokbase0+trow)*128 + cq);
    #pragma unroll
    for (int u=0; u<4; ++u) *(uint4*)&As[trow*136 + cq + u*8] = src[u];
  }
  {
    int orow = tid>>1, c2 = (tid&1)*64;
    const uint4* src = (const uint4*)(wb + WB_PW + (size_t)orow*128 + c2);
    #pragma unroll
    for (int u=0; u<8; ++u) *(uint4*)&Ws[orow*136 + c2 + u*8] = src[u];
  }
  __syncthreads();
  const int wave = tid>>6, lane = tid&63;
  const int c = lane & 15, g = lane >> 4;
  bf16x8 ka[4];
  #pragma unroll
  for (int kk=0; kk<4; ++kk)
    ka[kk] = *(const bf16x8*)&As[(wave*16 + c)*136 + kk*32 + g*8];
  f32x4 acc[8];
  #pragma unroll
  for (int nt=0; nt<8; ++nt) acc[nt] = 0.f;
  #pragma unroll
  for (int nt=0; nt<8; ++nt){
    #pragma unroll
    for (int kk=0; kk<4; ++kk){
      bf16x8 wf = *(const bf16x8*)&Ws[(nt*16 + c)*136 + kk*32 + g*8];
      acc[nt] = mfma16(ka[kk], wf, acc[nt]);
    }
  }
  const int tokbase = tokbase0 + wave*16;
  size_t po[4];
  #pragma unroll
  for (int r=0;r<4;++r){
    int gtok = tokbase + 4*g + r;
    int win = gtok/392, tt = gtok - win*392;
    int dwi = win>>6, hwi = (win>>3)&7, wwi = win&7;
    int td = tt/49; int r2 = tt - td*49; int th = r2/7; int tw = r2 - th*7;
    int pd = dwi*8 + td + 4; if (pd >= 16) pd -= 16;
    int ph = hwi*7 + th + 3; if (ph >= 56) ph -= 56;
    int pwx = wwi*7 + tw + 3; if (pwx >= 56) pwx -= 56;
    po[r] = (size_t)((pd*56 + ph)*56 + pwx)*128;
  }
  #pragma unroll
  for (int nt=0; nt<8; ++nt){
    int oc = nt*16 + c;
    float bv = b2f(wb[WB_PB + oc]);
    #pragma unroll
    for (int r=0;r<4;++r){
      float v = acc[nt][r] + bv;
      if (isf32) ((float*)out)[po[r] + oc] = v;
      else       ((u16*)out)[po[r] + oc] = f2b(v);
    }
  }
}

extern "C" void kernel_launch(void* const* d_in, const int* in_sizes, int n_in,
                              void* d_out, int out_size, void* d_ws, size_t ws_size,
                              hipStream_t stream){
  const void* x      = d_in[0];
  const void* qkv_w  = d_in[1];
  const void* qkv_b  = d_in[2];
  const void* proj_w = d_in[3];
  const void* proj_b = d_in[4];
  const void* lsc    = d_in[5];
  const void* cpb_w1 = d_in[6];
  const void* cpb_b1 = d_in[7];
  const void* cpb_w2 = d_in[8];
  char* ws = (char*)d_ws;
  int*   flag    = (int*)(ws);                       // 256 B
  float* table16 = (float*)(ws + 256);               // 40,960 B
  float* bias16  = (float*)(ws + 41216);             // 2,458,624 B
  u16*   wb      = (u16*)(ws + 2499840);             // 132,096 B
  u16*   qkvbuf  = (u16*)(ws + 2631936);             // 38,535,168 B
  u16*   attnout = (u16*)(ws + 41167104);            // 12,845,056 B

  k_detect<<<1, 256, 0, stream>>>((const u32*)x, flag);
  k_wconv<<<(WB_TOT+255)/256, 256, 0, stream>>>(qkv_w, proj_w, qkv_b, proj_b, flag, wb);
  k_cpb <<<TBL, 64, 0, stream>>>(cpb_w1, cpb_b1, cpb_w2, flag, table16);
  k_bias<<<dim3(392,4), 128, 0, stream>>>(table16, bias16);
  k_qkv <<<784, 256, 0, stream>>>(x, wb, flag, qkvbuf);
  k_attn<<<dim3(128,4), 512, 0, stream>>>(qkvbuf, bias16, lsc, flag, attnout);
  k_proj<<<784, 256, 0, stream>>>(attnout, wb, flag, d_out);
}

// Round 6
// 99.145 us; speedup vs baseline: 6.7240x; 1.0347x over previous
//
#include <hip/hip_runtime.h>
#include <hip/hip_bf16.h>

typedef unsigned short u16;
typedef unsigned int   u32;
typedef float f32x4  __attribute__((ext_vector_type(4)));
typedef short bf16x8 __attribute__((ext_vector_type(8)));

#define DI __device__ __forceinline__

constexpr int TBL  = 2535;     // (2*8-1)*(2*7-1)*(2*7-1)
constexpr int NTOK = 50176;    // 128 windows * 392 tokens
constexpr float L2E = 1.4426950408889634f;

// bf16 weight scratch layout (u16 units)
constexpr int WB_QW = 0;          // 49152
constexpr int WB_PW = 49152;      // 16384
constexpr int WB_QB = 65536;      // 384
constexpr int WB_PB = 65920;      // 128
constexpr int WB_TOT = 66048;

DI float b2f(u16 u){ return __uint_as_float(((u32)u)<<16); }
DI u16 f2b(float f){
  u32 u = __float_as_uint(f);
  return (u16)((u + 0x7fffu + ((u>>16)&1u)) >> 16);
}
DI float ldf(const void* p, int i, int isf32){
  return isf32 ? ((const float*)p)[i] : b2f(((const u16*)p)[i]);
}
DI f32x4 mfma16(bf16x8 a, bf16x8 b, f32x4 c){
  return __builtin_amdgcn_mfma_f32_16x16x32_bf16(a, b, c, 0, 0, 0);
}
DI u32 cvtpk(float lo, float hi){
  u32 r;
  asm("v_cvt_pk_bf16_f32 %0, %1, %2" : "=v"(r) : "v"(lo), "v"(hi));
  return r;
}
DI float vexp2(float x){
  float r;
  asm("v_exp_f32 %0, %1" : "=v"(r) : "v"(x));
  return r;
}

// ---------------- 0) dtype detector (f32 vs bf16 input buffers)
__global__ void k_detect(const u32* __restrict__ xw, int* __restrict__ flag){
  __shared__ int cnt;
  if (threadIdx.x == 0) cnt = 0;
  __syncthreads();
  int local = 0;
  for (int k = threadIdx.x; k < 4096; k += 256){
    u32 w = xw[k];
    u16 lo = (u16)w;
    u32 e = (lo >> 7) & 0xFF;
    if (lo != 0 && (e >= 143 || e <= 111)) local++;
  }
  atomicAdd(&cnt, local);
  __syncthreads();
  if (threadIdx.x == 0) *flag = (cnt > 1000) ? 1 : 0;
}

// ---------------- 1) CPB MLP table (value = (16*sigmoid - 15) * log2(e))
//                    + weight conversion to bf16 scratch (merged wconv)
__global__ void k_cpb(const void* __restrict__ w1, const void* __restrict__ b1,
                      const void* __restrict__ w2, const int* __restrict__ flag,
                      const void* __restrict__ qw, const void* __restrict__ pw,
                      const void* __restrict__ qb, const void* __restrict__ pb,
                      u16* __restrict__ wb, float* __restrict__ table16){
  const int isf32 = *flag;
  { // merged weight conversion
    int gid = blockIdx.x*64 + threadIdx.x;
    if (gid < WB_TOT){
      const void* src; int off;
      if (gid < WB_PW)      { src = qw; off = gid; }
      else if (gid < WB_QB) { src = pw; off = gid - WB_PW; }
      else if (gid < WB_PB) { src = qb; off = gid - WB_QB; }
      else                  { src = pb; off = gid - WB_PB; }
      wb[gid] = isf32 ? f2b(((const float*)src)[off]) : ((const u16*)src)[off];
    }
  }
  int t = blockIdx.x, lane = threadIdx.x;
  int i = t/169; int r = t - i*169; int j = r/13; int k = r - j*13;
  float v0 = 8.f*(float)(i-7)/7.f, v1 = 8.f*(float)(j-6)/6.f, v2 = 8.f*(float)(k-6)/6.f;
  float c0 = copysignf(log2f(fabsf(v0)+1.f)*(1.f/3.f), v0);
  float c1 = copysignf(log2f(fabsf(v1)+1.f)*(1.f/3.f), v1);
  float c2 = copysignf(log2f(fabsf(v2)+1.f)*(1.f/3.f), v2);
  float a0=0.f,a1=0.f,a2=0.f,a3=0.f;
  for (int hh = lane; hh < 512; hh += 64){
    float a = c0*ldf(w1,hh*3,isf32) + c1*ldf(w1,hh*3+1,isf32)
            + c2*ldf(w1,hh*3+2,isf32) + ldf(b1,hh,isf32);
    a = fmaxf(a, 0.f);
    a0 += a*ldf(w2,hh,isf32);       a1 += a*ldf(w2,512+hh,isf32);
    a2 += a*ldf(w2,1024+hh,isf32);  a3 += a*ldf(w2,1536+hh,isf32);
  }
  #pragma unroll
  for (int off=32; off; off>>=1){
    a0 += __shfl_xor(a0, off); a1 += __shfl_xor(a1, off);
    a2 += __shfl_xor(a2, off); a3 += __shfl_xor(a3, off);
  }
  if (lane==0){
    table16[t]       = (16.f/(1.f+__expf(-a0)) - 15.f)*L2E;
    table16[TBL+t]   = (16.f/(1.f+__expf(-a1)) - 15.f)*L2E;
    table16[2*TBL+t] = (16.f/(1.f+__expf(-a2)) - 15.f)*L2E;
    table16[3*TBL+t] = (16.f/(1.f+__expf(-a3)) - 15.f)*L2E;
  }
}

// ---------------- 2) expand to bias16[h][n][m] (f32, pre-scaled by log2e)
__global__ void k_bias(const float* __restrict__ table16, float* __restrict__ bias16){
  int n = blockIdx.x, h = blockIdx.y;
  int td = n/49; int r2 = n - td*49; int th = r2/7; int tw = r2 - th*7;
  const float* tb = table16 + h*TBL;
  float* o = bias16 + ((size_t)h*392 + n)*392;
  for (int m = threadIdx.x; m < 392; m += 128){
    int sd = m/49; int q2 = m - sd*49; int sh = q2/7; int sw = q2 - sh*7;
    int idx = (td - sd + 7)*169 + (th - sh + 6)*13 + (tw - sw + 6);
    o[m] = tb[idx];
  }
}

// ---------------- 3) QKV GEMM via MFMA + fused Q/K row-normalization
// Q rows scaled by scale_h*log2e; K rows normalized; V plain.
__global__ __launch_bounds__(256,3) void k_qkv(const void* __restrict__ x,
    const u16* __restrict__ wb, const void* __restrict__ lsc,
    const int* __restrict__ flag, u16* __restrict__ qkvbuf){
  __shared__ __align__(16) u16 As[64*136];   // [tok][k], stride 136
  __shared__ __align__(16) u16 Ws[128*136];  // [oc][k]
  const int isf32 = *flag;
  const int tid = threadIdx.x;
  const int tokbase0 = blockIdx.x*64;
  { // stage x rows (gather through roll+window mapping)
    int trow = tid>>2, cq = (tid&3)*32;
    int gtok = tokbase0 + trow;
    int win = gtok/392, tt = gtok - win*392;
    int dwi = win>>6, hwi = (win>>3)&7, wwi = win&7;
    int td = tt/49; int r2 = tt - td*49; int th = r2/7; int tw = r2 - th*7;
    int pd = dwi*8 + td + 4; if (pd >= 16) pd -= 16;
    int ph = hwi*7 + th + 3; if (ph >= 56) ph -= 56;
    int pw = wwi*7 + tw + 3; if (pw >= 56) pw -= 56;
    size_t pos = (size_t)((pd*56 + ph)*56 + pw)*128 + cq;
    if (isf32){
      const float4* src = (const float4*)((const float*)x + pos);
      #pragma unroll
      for (int u=0; u<8; ++u){
        float4 a = src[u];
        ushort4 s4 = make_ushort4(f2b(a.x), f2b(a.y), f2b(a.z), f2b(a.w));
        *(ushort4*)&As[trow*136 + cq + u*4] = s4;
      }
    } else {
      const uint4* src = (const uint4*)((const u16*)x + pos);
      #pragma unroll
      for (int u=0; u<4; ++u) *(uint4*)&As[trow*136 + cq + u*8] = src[u];
    }
  }
  const int wave = tid>>6, lane = tid&63;
  const int c = lane & 15, g = lane >> 4;
  const int tokbase = tokbase0 + wave*16;
  // per-head scale*log2e
  float sl2e[4];
  #pragma unroll
  for (int h2=0; h2<4; ++h2){
    float ls = ldf(lsc, h2, isf32);
    sl2e[h2] = __expf(fminf(ls, 4.60517019f)) * L2E;
  }
  bf16x8 ka[4];
  for (int which = 0; which < 3; ++which){
    __syncthreads();
    { // stage weight rows [which*128 .. +127] (bf16 preconverted)
      int orow = tid>>1, c2 = (tid&1)*64;
      const uint4* src = (const uint4*)(wb + WB_QW + (size_t)(which*128 + orow)*128 + c2);
      #pragma unroll
      for (int u=0; u<8; ++u) *(uint4*)&Ws[orow*136 + c2 + u*8] = src[u];
    }
    __syncthreads();
    if (which == 0){
      #pragma unroll
      for (int kk=0; kk<4; ++kk)
        ka[kk] = *(const bf16x8*)&As[(wave*16 + c)*136 + kk*32 + g*8];
    }
    f32x4 acc[8];
    #pragma unroll
    for (int nt=0; nt<8; ++nt) acc[nt] = 0.f;
    #pragma unroll
    for (int nt=0; nt<8; ++nt){
      #pragma unroll
      for (int kk=0; kk<4; ++kk){
        bf16x8 wf = *(const bf16x8*)&Ws[(nt*16 + c)*136 + kk*32 + g*8];
        acc[nt] = mfma16(ka[kk], wf, acc[nt]);
      }
    }
    // add bias (k-bias zeroed per Swin v2)
    if (which != 1){
      #pragma unroll
      for (int nt=0; nt<8; ++nt){
        float bv = b2f(wb[WB_QB + which*128 + nt*16 + c]);
        #pragma unroll
        for (int r=0;r<4;++r) acc[nt][r] += bv;
      }
    }
    // row-normalize q/k per head (reduce over the 16 c-lanes)
    if (which < 2){
      #pragma unroll
      for (int h2=0; h2<4; ++h2){
        f32x4 ss;
        #pragma unroll
        for (int r=0;r<4;++r)
          ss[r] = acc[2*h2][r]*acc[2*h2][r] + acc[2*h2+1][r]*acc[2*h2+1][r];
        #pragma unroll
        for (int off=1; off<16; off<<=1){
          #pragma unroll
          for (int r=0;r<4;++r) ss[r] += __shfl_xor(ss[r], off);
        }
        #pragma unroll
        for (int r=0;r<4;++r){
          float rn = rsqrtf(fmaxf(ss[r], 1e-24f));
          if (which == 0) rn *= sl2e[h2];
          acc[2*h2][r]   *= rn;
          acc[2*h2+1][r] *= rn;
        }
      }
    }
    #pragma unroll
    for (int nt=0; nt<8; ++nt){
      int oc = nt*16 + c;
      int head = oc >> 5, chb = oc & 31;
      #pragma unroll
      for (int r=0;r<4;++r){
        int t = tokbase + 4*g + r;
        qkvbuf[((size_t)(which*4+head)*NTOK + t)*32 + chb] = f2b(acc[nt][r]);
      }
    }
  }
}

// ---------------- 4) attention: swapped-operand MFMA, p = exp2(t + bias)
#define QKT_STEP(JT, JJ, TAIL, MIXED) do { \
  bf16x8 kf = *(const bf16x8*)&klds[((JT)*16 + c)*40 + g*8]; \
  f32x4 tz = {0.f,0.f,0.f,0.f}; \
  f32x4 t = mfma16(kf, qf, tz); \
  const int mb = (JT)*16 + 4*g; \
  const int mbc = (TAIL) ? ((mb <= 388) ? mb : 388) : mb; \
  const float4 bq = *(const float4*)(brow + mbc); \
  float p0 = vexp2(t[0] + bq.x); \
  float p1 = vexp2(t[1] + bq.y); \
  float p2 = vexp2(t[2] + bq.z); \
  float p3 = vexp2(t[3] + bq.w); \
  if (MIXED){ \
    const int4 cmq = *(const int4*)&cnt[mbc]; \
    if (cmq.x != cn) p0 = 0.f; \
    if (cmq.y != cn) p1 = 0.f; \
    if (cmq.z != cn) p2 = 0.f; \
    if (cmq.w != cn) p3 = 0.f; \
  } \
  if (TAIL && mb > 388){ p0=0.f; p1=0.f; p2=0.f; p3=0.f; } \
  uint2 wv; wv.x = cvtpk(p0,p1); wv.y = cvtpk(p2,p3); \
  *(uint2*)&psw[c*20 + (JJ)*8 + 2*g] = wv; \
} while(0)

#define PV_STEP(MC) do { \
  bf16x8 pf = *(const bf16x8*)&psw[c*20 + 4*g]; \
  bf16x8 va = *(const bf16x8*)&vT[c*424 + (MC)*32 + g*8]; \
  bf16x8 vb = *(const bf16x8*)&vT[(16+c)*424 + (MC)*32 + g*8]; \
  o0 = mfma16(va, pf, o0); \
  o1 = mfma16(vb, pf, o1); \
  o2 = mfma16(ones, pf, o2); \
} while(0)

template<bool MIXED>
DI void attn_main(const u16* __restrict__ qg, const float* __restrict__ bias_h,
                  const u16* klds, const u16* vT, u32* psw, const int* cnt,
                  u16* __restrict__ aout, int win, int h, int wave, int lane){
  const int c = lane & 15, g = lane >> 4;
  const short ob = 0x3F80;
  const bf16x8 ones = {ob,ob,ob,ob,ob,ob,ob,ob};
  for (int rt = wave; rt < 25; rt += 8){
    const int nb = rt*16;
    const int nc = (nb + c < 392) ? (nb + c) : 391;
    const bf16x8 qf = *(const bf16x8*)(qg + (size_t)nc*32 + g*8);
    const int cn = MIXED ? cnt[nc] : 0;
    const float* brow = bias_h + (size_t)nc*392;
    f32x4 o0 = {0.f,0.f,0.f,0.f}, o1 = {0.f,0.f,0.f,0.f}, o2 = {0.f,0.f,0.f,0.f};
    for (int mc = 0; mc < 12; ++mc){
      QKT_STEP(2*mc,   0, false, MIXED);
      QKT_STEP(2*mc+1, 1, false, MIXED);
      PV_STEP(mc);
    }
    QKT_STEP(24, 0, true, MIXED);
    { uint2 zz; zz.x = 0u; zz.y = 0u; *(uint2*)&psw[c*20 + 8 + 2*g] = zz; }
    PV_STEP(12);
    // normalize + coalesced store via LDS bounce
    const float rv = 1.f / o2[0];
    uint2 wa, wb2;
    wa.x  = cvtpk(o0[0]*rv, o0[1]*rv);  wa.y  = cvtpk(o0[2]*rv, o0[3]*rv);
    wb2.x = cvtpk(o1[0]*rv, o1[1]*rv);  wb2.y = cvtpk(o1[2]*rv, o1[3]*rv);
    *(uint2*)&psw[c*20 + 2*g]     = wa;
    *(uint2*)&psw[c*20 + 8 + 2*g] = wb2;
    const int orow = lane>>2, oq = lane&3;
    uint4 ov = *(const uint4*)&psw[orow*20 + 4*oq];
    const int n = nb + orow;
    if (n < 392)
      *(uint4*)(aout + ((size_t)(win*392 + n))*128 + h*32 + oq*8) = ov;
  }
}

__global__ __launch_bounds__(512,4) void k_attn(const u16* __restrict__ qkv,
    const float* __restrict__ bias16, u16* __restrict__ aout){
  __shared__ __align__(16) u16 klds[400*40];   // K-hat rows [m][k] (32000 B)
  __shared__ __align__(16) u16 vT[32*424];     // V^T [ch][m] (27136 B)
  __shared__ __align__(16) u32 ps[8][16*20];   // per-wave P/O scratch (10240 B)
  __shared__ __align__(16) int cnt[400];       // region ids (1600 B)
  const int tid = threadIdx.x;
  const int win = blockIdx.x, h = blockIdx.y;
  const int dwi = win>>6, hwi = (win>>3)&7, wwi = win&7;
  const u16* qg = qkv + ((size_t)(0*4 + h)*NTOK + (size_t)win*392)*32;
  const u16* kg = qkv + ((size_t)(1*4 + h)*NTOK + (size_t)win*392)*32;
  const u16* vg = qkv + ((size_t)(2*4 + h)*NTOK + (size_t)win*392)*32;
  // ---- stage K-hat rows (plain copy, zeros for rows >= 392)
  for (int idx = tid; idx < 1600; idx += 512){
    const int row = idx>>2, q = idx&3;
    uint4 a = {0,0,0,0};
    if (row < 392) a = *(const uint4*)(kg + (size_t)row*32 + q*8);
    *(uint4*)&klds[row*40 + q*8] = a;
  }
  // ---- stage V transposed: 4-row register repack (b64 writes along m)
  for (int idx = tid; idx < 784; idx += 512){
    const int mg = idx>>3, cg = idx&7;   // mg: 4-row group, cg: 4-ch group
    uint2 v0 = *(const uint2*)(vg + (size_t)(4*mg+0)*32 + cg*4);
    uint2 v1 = *(const uint2*)(vg + (size_t)(4*mg+1)*32 + cg*4);
    uint2 v2 = *(const uint2*)(vg + (size_t)(4*mg+2)*32 + cg*4);
    uint2 v3 = *(const uint2*)(vg + (size_t)(4*mg+3)*32 + cg*4);
    u16 e0[4], e1[4], e2[4], e3[4];
    e0[0]=(u16)v0.x; e0[1]=(u16)(v0.x>>16); e0[2]=(u16)v0.y; e0[3]=(u16)(v0.y>>16);
    e1[0]=(u16)v1.x; e1[1]=(u16)(v1.x>>16); e1[2]=(u16)v1.y; e1[3]=(u16)(v1.y>>16);
    e2[0]=(u16)v2.x; e2[1]=(u16)(v2.x>>16); e2[2]=(u16)v2.y; e2[3]=(u16)(v2.y>>16);
    e3[0]=(u16)v3.x; e3[1]=(u16)(v3.x>>16); e3[2]=(u16)v3.y; e3[3]=(u16)(v3.y>>16);
    #pragma unroll
    for (int cc=0; cc<4; ++cc){
      ushort4 w = make_ushort4(e0[cc], e1[cc], e2[cc], e3[cc]);
      *(ushort4*)&vT[(cg*4+cc)*424 + 4*mg] = w;
    }
  }
  for (int idx = tid; idx < 1024; idx += 512){
    int ch = idx>>5, mm = 392 + (idx&31);
    vT[ch*424 + mm] = 0;
  }
  // ---- region ids
  for (int t2 = tid; t2 < 400; t2 += 512){
    int row = (t2 < 392) ? t2 : 391;
    int td = row/49; int r2 = row - td*49; int th = r2/7; int tw = r2 - th*7;
    int gd = dwi*8 + td, gh = hwi*7 + th, gw = wwi*7 + tw;
    int rd = (gd < 8) ? 0 : ((gd < 12) ? 1 : 2);
    int rh = (gh < 49) ? 0 : ((gh < 53) ? 1 : 2);
    int rw = (gw < 49) ? 0 : ((gw < 53) ? 1 : 2);
    cnt[t2] = rd*9 + rh*3 + rw;
  }
  __syncthreads();
  const int wave = tid>>6, lane = tid&63;
  u32* psw = &ps[wave][0];
  const float* bias_h = bias16 + (size_t)h*153664;
  const bool uniform = (dwi == 0) && (hwi < 7) && (wwi < 7);
  if (uniform)
    attn_main<false>(qg, bias_h, klds, vT, psw, cnt, aout, win, h, wave, lane);
  else
    attn_main<true >(qg, bias_h, klds, vT, psw, cnt, aout, win, h, wave, lane);
}

// ---------------- 5) projection GEMM via MFMA + window reverse + roll-back
__global__ __launch_bounds__(256,2) void k_proj(const u16* __restrict__ ain,
    const u16* __restrict__ wb, const int* __restrict__ flag, void* __restrict__ out){
  __shared__ __align__(16) u16 As[64*136];
  __shared__ __align__(16) u16 Ws[128*136];
  const int isf32 = *flag;
  const int tid = threadIdx.x;
  const int tokbase0 = blockIdx.x*64;
  {
    int trow = tid>>2, cq = (tid&3)*32;
    const uint4* src = (const uint4*)(ain + (size_t)(tokbase0+trow)*128 + cq);
    #pragma unroll
    for (int u=0; u<4; ++u) *(uint4*)&As[trow*136 + cq + u*8] = src[u];
  }
  {
    int orow = tid>>1, c2 = (tid&1)*64;
    const uint4* src = (const uint4*)(wb + WB_PW + (size_t)orow*128 + c2);
    #pragma unroll
    for (int u=0; u<8; ++u) *(uint4*)&Ws[orow*136 + c2 + u*8] = src[u];
  }
  __syncthreads();
  const int wave = tid>>6, lane = tid&63;
  const int c = lane & 15, g = lane >> 4;
  bf16x8 ka[4];
  #pragma unroll
  for (int kk=0; kk<4; ++kk)
    ka[kk] = *(const bf16x8*)&As[(wave*16 + c)*136 + kk*32 + g*8];
  f32x4 acc[8];
  #pragma unroll
  for (int nt=0; nt<8; ++nt) acc[nt] = 0.f;
  #pragma unroll
  for (int nt=0; nt<8; ++nt){
    #pragma unroll
    for (int kk=0; kk<4; ++kk){
      bf16x8 wf = *(const bf16x8*)&Ws[(nt*16 + c)*136 + kk*32 + g*8];
      acc[nt] = mfma16(ka[kk], wf, acc[nt]);
    }
  }
  const int tokbase = tokbase0 + wave*16;
  size_t po[4];
  #pragma unroll
  for (int r=0;r<4;++r){
    int gtok = tokbase + 4*g + r;
    int win = gtok/392, tt = gtok - win*392;
    int dwi = win>>6, hwi = (win>>3)&7, wwi = win&7;
    int td = tt/49; int r2 = tt - td*49; int th = r2/7; int tw = r2 - th*7;
    int pd = dwi*8 + td + 4; if (pd >= 16) pd -= 16;
    int ph = hwi*7 + th + 3; if (ph >= 56) ph -= 56;
    int pwx = wwi*7 + tw + 3; if (pwx >= 56) pwx -= 56;
    po[r] = (size_t)((pd*56 + ph)*56 + pwx)*128;
  }
  #pragma unroll
  for (int nt=0; nt<8; ++nt){
    int oc = nt*16 + c;
    float bv = b2f(wb[WB_PB + oc]);
    #pragma unroll
    for (int r=0;r<4;++r){
      float v = acc[nt][r] + bv;
      if (isf32) ((float*)out)[po[r] + oc] = v;
      else       ((u16*)out)[po[r] + oc] = f2b(v);
    }
  }
}

extern "C" void kernel_launch(void* const* d_in, const int* in_sizes, int n_in,
                              void* d_out, int out_size, void* d_ws, size_t ws_size,
                              hipStream_t stream){
  const void* x      = d_in[0];
  const void* qkv_w  = d_in[1];
  const void* qkv_b  = d_in[2];
  const void* proj_w = d_in[3];
  const void* proj_b = d_in[4];
  const void* lsc    = d_in[5];
  const void* cpb_w1 = d_in[6];
  const void* cpb_b1 = d_in[7];
  const void* cpb_w2 = d_in[8];
  char* ws = (char*)d_ws;
  int*   flag    = (int*)(ws);                       // 256 B
  float* table16 = (float*)(ws + 256);               // 40,960 B
  float* bias16  = (float*)(ws + 41216);             // 2,458,624 B
  u16*   wb      = (u16*)(ws + 2499840);             // 132,096 B
  u16*   qkvbuf  = (u16*)(ws + 2631936);             // 38,535,168 B
  u16*   attnout = (u16*)(ws + 41167104);            // 12,845,056 B

  k_detect<<<1, 256, 0, stream>>>((const u32*)x, flag);
  k_cpb <<<TBL, 64, 0, stream>>>(cpb_w1, cpb_b1, cpb_w2, flag,
                                 qkv_w, proj_w, qkv_b, proj_b, wb, table16);
  k_bias<<<dim3(392,4), 128, 0, stream>>>(table16, bias16);
  k_qkv <<<784, 256, 0, stream>>>(x, wb, lsc, flag, qkvbuf);
  k_attn<<<dim3(128,4), 512, 0, stream>>>(qkvbuf, bias16, attnout);
  k_proj<<<784, 256, 0, stream>>>(attnout, wb, flag, d_out);
}